// Round 5
// baseline (27.349 us; speedup 1.0000x reference)
//
#include <hip/hip_runtime.h>
#include <math.h>

#define N_ 16
#define P_ 2048
#define K_ 512
#define H_ 256
#define W_ 256
#define HW_ (H_ * W_)
#define ZT_ 2.0f
#define GBLK_ 128  // gather blocks in K1 (128*256 == N_*P_)
#define KB_ 32     // vote blocks per n
#define KPB_ 16    // k's per vote block (KB_*KPB_ == K_)

// ---------------------------------------------------------------------------
// K1: precompute (144 blocks x 256 threads).
//  blocks [0,128): gather uv at all N*P pts -> uvp (scattered reads ONCE).
//  blocks [128,144): per-n: solve all 512 Y (Cramer; pinv==inv a.e.),
//  per-n mean/std (ddof=1) -> bad flags; zero done[n].
// ---------------------------------------------------------------------------
__global__ __launch_bounds__(256) void k_pre(
    const float* __restrict__ uv_img, const int* __restrict__ pts,
    const int* __restrict__ pair, float2* __restrict__ uvp,
    float2* __restrict__ Yg, int* __restrict__ bad, int* __restrict__ done) {
  int tid = threadIdx.x;
  if (blockIdx.x < GBLK_) {
    int id = blockIdx.x * 256 + tid;  // id == n*P_ + p
    int2 c = ((const int2*)pts)[id];
    const float* base = uv_img + (size_t)(id >> 11) * 2 * HW_;
    int o = c.x * W_ + c.y;
    uvp[id] = make_float2(base[o], base[HW_ + o]);
    return;
  }
  int n = blockIdx.x - GBLK_;
  if (tid == 0) done[n] = 0;
  const int2* pts2 = (const int2*)pts + n * P_;
  const int2* pr2 = (const int2*)pair + n * K_;
  const float* base = uv_img + (size_t)n * 2 * HW_;

  float2 ya, yb;
#pragma unroll
  for (int h = 0; h < 2; h++) {
    int k = tid + h * 256;
    int2 pr = pr2[k];
    int2 p0 = pts2[pr.x];
    int2 p1 = pts2[pr.y];
    float u00 = base[p0.x * W_ + p0.y];
    float u01 = base[HW_ + p0.x * W_ + p0.y];
    float u10 = base[p1.x * W_ + p1.y];
    float u11 = base[HW_ + p1.x * W_ + p1.y];
    float B0 = (float)(p1.x - p0.x);
    float B1 = (float)(p1.y - p0.y);
    float det = u10 * u01 - u00 * u11;
    float x0 = (u10 * B1 - B0 * u11) / det;
    float2 y = make_float2(x0 * u00 + (float)p0.x, x0 * u01 + (float)p0.y);
    if (h == 0) ya = y; else yb = y;
    Yg[n * K_ + k] = y;
  }

  // stats over the 512 Y of this n (2 per thread); NaN propagates like jnp.
  __shared__ float red[4][2];
  __shared__ float bc[4];
  int wave = tid >> 6, lane = tid & 63;
  float a0 = ya.x + yb.x, a1 = ya.y + yb.y;
  for (int off = 32; off >= 1; off >>= 1) {
    a0 += __shfl_down(a0, off);
    a1 += __shfl_down(a1, off);
  }
  if (lane == 0) { red[wave][0] = a0; red[wave][1] = a1; }
  __syncthreads();
  if (tid == 0) {
    float t0 = red[0][0] + red[1][0] + red[2][0] + red[3][0];
    float t1 = red[0][1] + red[1][1] + red[2][1] + red[3][1];
    bc[0] = t0 / (float)K_;
    bc[1] = t1 / (float)K_;
  }
  __syncthreads();
  float m0 = bc[0], m1 = bc[1];
  float ea0 = ya.x - m0, ea1 = ya.y - m1;
  float eb0 = yb.x - m0, eb1 = yb.y - m1;
  a0 = ea0 * ea0 + eb0 * eb0;
  a1 = ea1 * ea1 + eb1 * eb1;
  for (int off = 32; off >= 1; off >>= 1) {
    a0 += __shfl_down(a0, off);
    a1 += __shfl_down(a1, off);
  }
  if (lane == 0) { red[wave][0] = a0; red[wave][1] = a1; }
  __syncthreads();
  if (tid == 0) {
    float t0 = red[0][0] + red[1][0] + red[2][0] + red[3][0];
    float t1 = red[0][1] + red[1][1] + red[2][1] + red[3][1];
    bc[2] = sqrtf(t0 / (float)(K_ - 1));
    bc[3] = sqrtf(t1 / (float)(K_ - 1));
  }
  __syncthreads();
  float sd0 = bc[2], sd1 = bc[3];
  int bda = (fabsf(ea0 / sd0) > ZT_) | (fabsf(ea1 / sd1) > ZT_) |
            (ya.x != ya.x) | (ya.y != ya.y);
  int bdb = (fabsf(eb0 / sd0) > ZT_) | (fabsf(eb1 / sd1) > ZT_) |
            (yb.x != yb.x) | (yb.y != yb.y);
  bad[n * K_ + tid] = bda;
  bad[n * K_ + tid + 256] = bdb;
}

// ---------------------------------------------------------------------------
// K2: votes (512 blocks x 256 threads), register-blocked, NO LDS in the hot
// loop. b -> n = b>>5, kt = b&31 (16 k's). Each thread holds 8 points
// {u,v,c=p.uv,pk} in registers (coalesced loads); the block's 16 yk/mk are
// uniform (scalar regs). 16x8 pairs/thread of pure VALU:
//   sign(yk.uv - c) == sign((yk-p).uv) == reference's normalized-dot sign
// (positive-norm division preserves sign; inf/NaN rows are 'bad' -> w=0).
// Counts pack into u32 (cnt + hm<<16; both <= 2048, no overflow). Butterfly
// reduce per wave, LDS combine, then one release-RMW per block; last arriver
// per n combines the 32 partials in fixed order and writes out[n].
// ---------------------------------------------------------------------------
__global__ __launch_bounds__(256) void k_vote(
    const int* __restrict__ pts, const float2* __restrict__ uvp,
    const float2* __restrict__ Yg, const int* __restrict__ bad,
    float* __restrict__ pw, float* __restrict__ ps0, float* __restrict__ ps1,
    int* __restrict__ done, float* __restrict__ out) {
  int b = blockIdx.x, tid = threadIdx.x;
  int n = b >> 5, kt = b & (KB_ - 1);
  int wave = tid >> 6, lane = tid & 63;
  __shared__ unsigned redc[4][KPB_];
  __shared__ float red[4][3];
  __shared__ int sflag;

  // 16 yk (uniform across block -> scalar regs) and match keys
  float ykx[KPB_], yky[KPB_];
  int mk[KPB_];
#pragma unroll
  for (int j = 0; j < KPB_; j++) {
    float2 y = Yg[n * K_ + kt * KPB_ + j];
    ykx[j] = y.x;
    yky[j] = y.y;
    int iy0 = (int)y.x, iy1 = (int)y.y;
    mk[j] = (((unsigned)iy0 < 256u) & ((unsigned)iy1 < 256u))
                ? ((iy0 << 8) | iy1) : -1;
  }

  const int2* pts2 = (const int2*)pts + n * P_;
  const float2* uvn = uvp + n * P_;
  unsigned acc[KPB_];
#pragma unroll
  for (int j = 0; j < KPB_; j++) acc[j] = 0u;

#pragma unroll
  for (int i = 0; i < P_ / 256; i++) {
    int p = i * 256 + tid;
    int2 pc = pts2[p];
    float2 uc = uvn[p];
    float c = fmaf((float)pc.x, uc.x, (float)pc.y * uc.y);
    int pk = (pc.x << 8) | pc.y;
#pragma unroll
    for (int j = 0; j < KPB_; j++) {
      float dot = fmaf(ykx[j], uc.x, fmaf(yky[j], uc.y, -c));
      acc[j] += (dot > 0.f ? 1u : 0u) + (pk == mk[j] ? 0x10000u : 0u);
    }
  }

  // wave butterfly: every lane ends with the wave total per k
#pragma unroll
  for (int j = 0; j < KPB_; j++) {
    unsigned a = acc[j];
    for (int off = 32; off >= 1; off >>= 1)
      a += (unsigned)__shfl_xor((int)a, off);
    acc[j] = a;
  }
  if (lane == 0) {
#pragma unroll
    for (int j = 0; j < KPB_; j++) redc[wave][j] = acc[j];
  }
  __syncthreads();

  float w = 0.f, s0 = 0.f, s1 = 0.f;
  if (tid < KPB_) {
    unsigned t = redc[0][tid] + redc[1][tid] + redc[2][tid] + redc[3][tid];
    int cnt = (int)(t & 0xFFFFu), hm = (int)(t >> 16);
    int k = kt * KPB_ + tid;
    if (!bad[n * K_ + k]) {
      float2 y = Yg[n * K_ + k];
      w = (float)cnt * ((hm == 1) ? 5.0f : 1.0f);  // MULT
      s0 = w * y.x;
      s1 = w * y.y;
    }
    for (int off = 8; off >= 1; off >>= 1) {
      w += __shfl_down(w, off, 16);
      s0 += __shfl_down(s0, off, 16);
      s1 += __shfl_down(s1, off, 16);
    }
  }
  if (tid == 0) {
    pw[b] = w;
    ps0[b] = s0;
    ps1[b] = s1;
    int old = __hip_atomic_fetch_add(&done[n], 1, __ATOMIC_ACQ_REL,
                                     __HIP_MEMORY_SCOPE_AGENT);
    sflag = (old == KB_ - 1);
  }
  __syncthreads();
  if (sflag && tid < KB_) {
    int i = (n << 5) + tid;
    float fw = __hip_atomic_load(&pw[i], __ATOMIC_RELAXED,
                                 __HIP_MEMORY_SCOPE_AGENT);
    float f0 = __hip_atomic_load(&ps0[i], __ATOMIC_RELAXED,
                                 __HIP_MEMORY_SCOPE_AGENT);
    float f1 = __hip_atomic_load(&ps1[i], __ATOMIC_RELAXED,
                                 __HIP_MEMORY_SCOPE_AGENT);
    for (int off = 16; off >= 1; off >>= 1) {
      fw += __shfl_down(fw, off, 32);
      f0 += __shfl_down(f0, off, 32);
      f1 += __shfl_down(f1, off, 32);
    }
    if (tid == 0) {
      float den = fmaxf(fw, 1.0f);
      out[n * 2 + 0] = f1 / den;  // pixel_xy reverses coord order
      out[n * 2 + 1] = f0 / den;
    }
  }
}

extern "C" void kernel_launch(void* const* d_in, const int* in_sizes, int n_in,
                              void* d_out, int out_size, void* d_ws,
                              size_t ws_size, hipStream_t stream) {
  const float* uv_img = (const float*)d_in[0];
  const int* pts = (const int*)d_in[1];
  const int* pair = (const int*)d_in[2];
  float* out = (float*)d_out;

  float2* uvp = (float2*)d_ws;          // N*P float2
  float2* Yg = uvp + N_ * P_;           // N*K float2
  int* bad = (int*)(Yg + N_ * K_);      // N*K int
  float* pw = (float*)(bad + N_ * K_);  // N*KB_
  float* ps0 = pw + N_ * KB_;           // N*KB_
  float* ps1 = ps0 + N_ * KB_;          // N*KB_
  int* done = (int*)(ps1 + N_ * KB_);   // N_

  hipLaunchKernelGGL(k_pre, dim3(GBLK_ + N_), dim3(256), 0, stream, uv_img,
                     pts, pair, uvp, Yg, bad, done);
  hipLaunchKernelGGL(k_vote, dim3(N_ * KB_), dim3(256), 0, stream, pts, uvp,
                     Yg, bad, pw, ps0, ps1, done, out);
}